// Round 1
// baseline (92.498 us; speedup 1.0000x reference)
//
#include <hip/hip_runtime.h>
#include <cstddef>

// cos(k*pi/16) base values (double, cast to f32 at compile time)
#define CD1 0.9807852804032304
#define CD2 0.9238795325112867
#define CD3 0.8314696123025452
#define CD4 0.7071067811865476
#define CD5 0.5555702330196022
#define CD6 0.3826834323650898
#define CD7 0.19509032201612825

__global__ __launch_bounds__(256) void diffjpeg_kernel(const float* __restrict__ in,
                                                       float* __restrict__ out)
{
    // CT[x][u] = cos((2x+1)*u*pi/16)
    const float CT[8][8] = {
      {1.0f,(float)CD1,(float)CD2,(float)CD3,(float)CD4,(float)CD5,(float)CD6,(float)CD7},
      {1.0f,(float)CD3,(float)CD6,(float)(-CD7),(float)(-CD4),(float)(-CD1),(float)(-CD2),(float)(-CD5)},
      {1.0f,(float)CD5,(float)(-CD6),(float)(-CD1),(float)(-CD4),(float)CD7,(float)CD2,(float)CD3},
      {1.0f,(float)CD7,(float)(-CD2),(float)(-CD5),(float)CD4,(float)CD3,(float)(-CD6),(float)(-CD1)},
      {1.0f,(float)(-CD7),(float)(-CD2),(float)CD5,(float)CD4,(float)(-CD3),(float)(-CD6),(float)CD1},
      {1.0f,(float)(-CD5),(float)(-CD6),(float)CD1,(float)(-CD4),(float)(-CD7),(float)CD2,(float)(-CD3)},
      {1.0f,(float)(-CD3),(float)CD6,(float)CD7,(float)(-CD4),(float)CD1,(float)(-CD2),(float)CD5},
      {1.0f,(float)(-CD1),(float)CD2,(float)(-CD3),(float)CD4,(float)(-CD5),(float)CD6,(float)(-CD7)}
    };
    // The python listing of _Y_TABLE BEFORE the .T  (so y_tab[u][v] = YL[v][u]*0.4)
    const int YL[8][8] = {
      {16,11,10,16,24,40,51,61},
      {12,12,14,19,26,58,60,55},
      {14,13,16,24,40,57,69,56},
      {14,17,22,29,51,87,80,62},
      {18,22,37,56,68,109,103,77},
      {24,35,55,64,81,104,113,92},
      {49,64,78,87,103,121,120,101},
      {72,92,95,98,112,100,103,99}
    };
    const double ALD[8] = {0.7071067811865476,1.0,1.0,1.0,1.0,1.0,1.0,1.0};

    const int t  = blockIdx.x * 256 + threadIdx.x;   // one thread = one 8x8 block
    if (t >= 393216) return;
    const int bw = t & 127;          // W-block col
    const int bh = (t >> 7) & 127;   // H-block row
    const int bc = t >> 14;          // b*3 + c, 0..23
    const int ch = bc % 3;
    const int bb = bc / 3;

    const float* src = in + ((size_t)bc * 1024 + (size_t)bh * 8) * 1024 + (size_t)bw * 8;

    // ---- stage 1: tmp[u][y] = sum_x CT[x][u] * (in*255-128)[x][y] ----
    float tmp[8][8];
#pragma unroll
    for (int u = 0; u < 8; ++u)
#pragma unroll
      for (int y = 0; y < 8; ++y) tmp[u][y] = 0.0f;

#pragma unroll
    for (int x = 0; x < 8; ++x) {
        const float4 r0 = *reinterpret_cast<const float4*>(src + (size_t)x * 1024);
        const float4 r1 = *reinterpret_cast<const float4*>(src + (size_t)x * 1024 + 4);
        float row[8] = {r0.x, r0.y, r0.z, r0.w, r1.x, r1.y, r1.z, r1.w};
#pragma unroll
        for (int y = 0; y < 8; ++y) row[y] = row[y] * 255.0f - 128.0f;
#pragma unroll
        for (int u = 0; u < 8; ++u) {
            const float cu = CT[x][u];
#pragma unroll
            for (int y = 0; y < 8; ++y) tmp[u][y] = fmaf(cu, row[y], tmp[u][y]);
        }
    }

    // ---- stage 2: dct, quantize (diff_round), store q; keep dequant*alpha*0.25 in tmp ----
    float* qout = out + (size_t)ch * 8388608 + (size_t)bb * 1048576
                      + ((size_t)(bh * 128 + bw)) * 64;

#pragma unroll
    for (int u = 0; u < 8; ++u) {
        float dr[8];
#pragma unroll
        for (int v = 0; v < 8; ++v) {
            float s = 0.0f;
#pragma unroll
            for (int y = 0; y < 8; ++y) s = fmaf(tmp[u][y], CT[y][v], s);
            dr[v] = s;
        }
        float qv[8];
#pragma unroll
        for (int v = 0; v < 8; ++v) {
            const float sc = (float)(ALD[u] * ALD[v] * 0.25);     // _SCALE[u][v]
            const float qt = (float)((double)YL[v][u] * 0.4);     // y_tab[u][v]
            const float xq = (sc * dr[v]) / qt;
            const float r  = rintf(xq);                           // round half-to-even
            const float d  = xq - r;
            qv[v] = r + d * d * d;
        }
        *reinterpret_cast<float4*>(qout + u * 8)     = make_float4(qv[0], qv[1], qv[2], qv[3]);
        *reinterpret_cast<float4*>(qout + u * 8 + 4) = make_float4(qv[4], qv[5], qv[6], qv[7]);
#pragma unroll
        for (int v = 0; v < 8; ++v) {
            const float qt = (float)((double)YL[v][u] * 0.4);
            const float al = (float)(ALD[u] * ALD[v]);            // _ALPHA[u][v]
            tmp[u][v] = ((qv[v] * qt) * al) * 0.25f;              // deq*alpha*0.25
        }
    }

    // ---- stage 3: IDCT rows, +128, clip, /255, store rec ----
    float* rout = out + (size_t)25165824
                      + ((size_t)bc * 1024 + (size_t)bh * 8) * 1024 + (size_t)bw * 8;

#pragma unroll
    for (int x = 0; x < 8; ++x) {
        float t2[8];
#pragma unroll
        for (int v = 0; v < 8; ++v) t2[v] = 0.0f;
#pragma unroll
        for (int u = 0; u < 8; ++u) {
            const float cxu = CT[x][u];
#pragma unroll
            for (int v = 0; v < 8; ++v) t2[v] = fmaf(cxu, tmp[u][v], t2[v]);
        }
        float orow[8];
#pragma unroll
        for (int y = 0; y < 8; ++y) {
            float s = 0.0f;
#pragma unroll
            for (int v = 0; v < 8; ++v) s = fmaf(t2[v], CT[y][v], s);
            s += 128.0f;
            s = fminf(fmaxf(s, 0.0f), 255.0f);
            orow[y] = s * (1.0f / 255.0f);
        }
        *reinterpret_cast<float4*>(rout + (size_t)x * 1024)     = make_float4(orow[0], orow[1], orow[2], orow[3]);
        *reinterpret_cast<float4*>(rout + (size_t)x * 1024 + 4) = make_float4(orow[4], orow[5], orow[6], orow[7]);
    }
}

extern "C" void kernel_launch(void* const* d_in, const int* in_sizes, int n_in,
                              void* d_out, int out_size, void* d_ws, size_t ws_size,
                              hipStream_t stream) {
    const float* x   = (const float*)d_in[0];
    float*       o   = (float*)d_out;
    // 8*3*128*128 = 393216 blocks, 256 threads each -> 1536 workgroups
    diffjpeg_kernel<<<1536, 256, 0, stream>>>(x, o);
}

// Round 2
// 76.688 us; speedup vs baseline: 1.2062x; 1.2062x over previous
//
#include <hip/hip_runtime.h>
#include <cstddef>

// cos(k*pi/16) base values (double, folded to f32 at compile time)
#define CD1 0.9807852804032304
#define CD2 0.9238795325112867
#define CD3 0.8314696123025452
#define CD4 0.7071067811865476
#define CD5 0.5555702330196022
#define CD6 0.3826834323650898
#define CD7 0.19509032201612825

__global__ __launch_bounds__(64) void diffjpeg_kernel(const float* __restrict__ in,
                                                      float* __restrict__ out)
{
    // per-wave staging buffer; row stride 20 dwords = 80 B (16B-aligned, bank-uniform)
    __shared__ float lds[64 * 20];

    // CT[x][u] = cos((2x+1)*u*pi/16)
    const float CT[8][8] = {
      {1.0f,(float)CD1,(float)CD2,(float)CD3,(float)CD4,(float)CD5,(float)CD6,(float)CD7},
      {1.0f,(float)CD3,(float)CD6,(float)(-CD7),(float)(-CD4),(float)(-CD1),(float)(-CD2),(float)(-CD5)},
      {1.0f,(float)CD5,(float)(-CD6),(float)(-CD1),(float)(-CD4),(float)CD7,(float)CD2,(float)CD3},
      {1.0f,(float)CD7,(float)(-CD2),(float)(-CD5),(float)CD4,(float)CD3,(float)(-CD6),(float)(-CD1)},
      {1.0f,(float)(-CD7),(float)(-CD2),(float)CD5,(float)CD4,(float)(-CD3),(float)(-CD6),(float)CD1},
      {1.0f,(float)(-CD5),(float)(-CD6),(float)CD1,(float)(-CD4),(float)(-CD7),(float)CD2,(float)(-CD3)},
      {1.0f,(float)(-CD3),(float)CD6,(float)CD7,(float)(-CD4),(float)CD1,(float)(-CD2),(float)CD5},
      {1.0f,(float)(-CD1),(float)CD2,(float)(-CD3),(float)CD4,(float)(-CD5),(float)CD6,(float)(-CD7)}
    };
    // python listing of _Y_TABLE BEFORE the .T (so y_tab[u][v] = YL[v][u]*0.4)
    const int YL[8][8] = {
      {16,11,10,16,24,40,51,61},
      {12,12,14,19,26,58,60,55},
      {14,13,16,24,40,57,69,56},
      {14,17,22,29,51,87,80,62},
      {18,22,37,56,68,109,103,77},
      {24,35,55,64,81,104,113,92},
      {49,64,78,87,103,121,120,101},
      {72,92,95,98,112,100,103,99}
    };
    const double ALD[8] = {0.7071067811865476,1.0,1.0,1.0,1.0,1.0,1.0,1.0};

    const int l  = threadIdx.x;              // lane 0..63 (one wave per workgroup)
    const int t  = blockIdx.x * 64 + l;      // one thread = one 8x8 block
    const int bw = t & 127;                  // W-block col
    const int bh = (t >> 7) & 127;           // H-block row (uniform across wave)
    const int bc = t >> 14;                  // b*3 + c   (uniform across wave)
    const int ch = bc % 3;
    const int bb = bc / 3;
    const int n0  = (blockIdx.x * 64) & 16383;  // first block-index of this wave
    const int bw0 = n0 & 127;

    const float* src = in + ((size_t)bc * 1024 + (size_t)bh * 8) * 1024 + (size_t)bw * 8;

    // ---- stage 1: tmp[u][y] = sum_x CT[x][u] * (in*255-128)[x][y] ----
    float tmp[8][8];
#pragma unroll
    for (int u = 0; u < 8; ++u)
#pragma unroll
      for (int y = 0; y < 8; ++y) tmp[u][y] = 0.0f;

#pragma unroll
    for (int x = 0; x < 8; ++x) {
        const float4 r0 = *reinterpret_cast<const float4*>(src + (size_t)x * 1024);
        const float4 r1 = *reinterpret_cast<const float4*>(src + (size_t)x * 1024 + 4);
        float row[8] = {r0.x, r0.y, r0.z, r0.w, r1.x, r1.y, r1.z, r1.w};
#pragma unroll
        for (int y = 0; y < 8; ++y) row[y] = row[y] * 255.0f - 128.0f;
#pragma unroll
        for (int u = 0; u < 8; ++u) {
            const float cu = CT[x][u];
#pragma unroll
            for (int y = 0; y < 8; ++y) tmp[u][y] = fmaf(cu, row[y], tmp[u][y]);
        }
    }

    // ---- stage 2: dct -> diff_round -> q (LDS-transposed coalesced store) ----
    // wave's q region: 64 consecutive 256-B records, 16 KB contiguous
    float* qwb = out + (size_t)ch * 8388608 + (size_t)bb * 1048576 + (size_t)n0 * 64;

#pragma unroll
    for (int u = 0; u < 8; ++u) {
        float dr[8];
#pragma unroll
        for (int v = 0; v < 8; ++v) {
            float s = 0.0f;
#pragma unroll
            for (int y = 0; y < 8; ++y) s = fmaf(tmp[u][y], CT[y][v], s);
            dr[v] = s;
        }
        float qv[8];
#pragma unroll
        for (int v = 0; v < 8; ++v) {
            // K = _SCALE[u][v] / y_tab[u][v]  (compile-time constant; replaces fdiv)
            const float K  = (float)((ALD[u] * ALD[v] * 0.25) / ((double)YL[v][u] * 0.4));
            const float xq = dr[v] * K;
            const float r  = rintf(xq);              // round half-to-even, matches jnp.round
            const float d  = xq - r;
            qv[v] = r + d * d * d;
        }
        // stage this u-row into LDS (two rows per coalesced flush)
        *reinterpret_cast<float4*>(&lds[l * 20 + (u & 1) * 8])     = make_float4(qv[0], qv[1], qv[2], qv[3]);
        *reinterpret_cast<float4*>(&lds[l * 20 + (u & 1) * 8 + 4]) = make_float4(qv[4], qv[5], qv[6], qv[7]);
        // keep dequant*alpha*0.25 for the IDCT (single folded constant)
#pragma unroll
        for (int v = 0; v < 8; ++v) {
            const float CDQ = (float)(((double)YL[v][u] * 0.4) * ALD[u] * ALD[v] * 0.25);
            tmp[u][v] = qv[v] * CDQ;
        }
        if (u & 1) {
            __syncthreads();
            const int up = u >> 1;   // chunk index 0..3, covers record bytes [up*64, up*64+64)
#pragma unroll
            for (int j = 0; j < 4; ++j) {
                const int m = j * 16 + (l >> 2);   // block-in-wave
                const float4 val = *reinterpret_cast<const float4*>(&lds[m * 20 + (l & 3) * 4]);
                // 4 lanes cover one full 64-B line of record m
                *reinterpret_cast<float4*>(&qwb[(size_t)m * 64 + up * 16 + (l & 3) * 4]) = val;
            }
            __syncthreads();
        }
    }

    // ---- stage 3: IDCT, +128, clip, /255 -> rec (LDS-staged coalesced rows) ----
    // wave's rec region per spatial row x: contiguous 2 KB
    float* rwb = out + (size_t)25165824
                     + ((size_t)bc * 1024 + (size_t)bh * 8) * 1024 + (size_t)bw0 * 8;

#pragma unroll
    for (int x = 0; x < 8; ++x) {
        float t2[8];
#pragma unroll
        for (int v = 0; v < 8; ++v) t2[v] = 0.0f;
#pragma unroll
        for (int u = 0; u < 8; ++u) {
            const float cxu = CT[x][u];
#pragma unroll
            for (int v = 0; v < 8; ++v) t2[v] = fmaf(cxu, tmp[u][v], t2[v]);
        }
        float orow[8];
#pragma unroll
        for (int y = 0; y < 8; ++y) {
            float s = 0.0f;
#pragma unroll
            for (int v = 0; v < 8; ++v) s = fmaf(t2[v], CT[y][v], s);
            s += 128.0f;
            s = fminf(fmaxf(s, 0.0f), 255.0f);
            orow[y] = s * (1.0f / 255.0f);
        }
        __syncthreads();
        *reinterpret_cast<float4*>(&lds[l * 20])     = make_float4(orow[0], orow[1], orow[2], orow[3]);
        *reinterpret_cast<float4*>(&lds[l * 20 + 4]) = make_float4(orow[4], orow[5], orow[6], orow[7]);
        __syncthreads();
#pragma unroll
        for (int j = 0; j < 2; ++j) {
            const int m = j * 32 + (l >> 1);    // block-in-wave owning these bytes
            const float4 val = *reinterpret_cast<const float4*>(&lds[m * 20 + (l & 1) * 4]);
            // wave writes a fully contiguous 1 KB per instruction
            *reinterpret_cast<float4*>(&rwb[(size_t)x * 1024 + j * 256 + l * 4]) = val;
        }
    }
}

extern "C" void kernel_launch(void* const* d_in, const int* in_sizes, int n_in,
                              void* d_out, int out_size, void* d_ws, size_t ws_size,
                              hipStream_t stream) {
    const float* x = (const float*)d_in[0];
    float*       o = (float*)d_out;
    // 393216 8x8-blocks, 64-thread (1-wave) workgroups -> 6144 workgroups
    diffjpeg_kernel<<<6144, 64, 0, stream>>>(x, o);
}

// Round 3
// 53.073 us; speedup vs baseline: 1.7428x; 1.4449x over previous
//
#include <hip/hip_runtime.h>
#include <cstddef>

// cos(k*pi/16) base values (double, folded to f32 at compile time)
#define CD1 0.9807852804032304
#define CD2 0.9238795325112867
#define CD3 0.8314696123025452
#define CD4 0.7071067811865476
#define CD5 0.5555702330196022
#define CD6 0.3826834323650898
#define CD7 0.19509032201612825

// python listing of _Y_TABLE BEFORE the .T, row-major: YLg[r*8+c]
// (so y_tab[u][v] = YLg[v*8+u] * 0.4)
__device__ const int YLg[64] = {
  16,11,10,16,24,40,51,61,
  12,12,14,19,26,58,60,55,
  14,13,16,24,40,57,69,56,
  14,17,22,29,51,87,80,62,
  18,22,37,56,68,109,103,77,
  24,35,55,64,81,104,113,92,
  49,64,78,87,103,121,120,101,
  72,92,95,98,112,100,103,99
};

// LDS map (floats):
//   [0, 2080)  image-chunk layout: 8 rows x 256 cols, row stride 260 (overlaps record region)
//   [0, 2176)  record layout: 32 blocks x 64, block stride 68
//   [2176, 2240) KQ table   [2240, 2304) KD table
__global__ __launch_bounds__(256) void diffjpeg_kernel(const float* __restrict__ in,
                                                       float* __restrict__ out)
{
    __shared__ float lds[2304];

    // CT[x][u] = cos((2x+1)*u*pi/16); all accesses compile-time after unroll
    const float CT[8][8] = {
      {1.0f,(float)CD1,(float)CD2,(float)CD3,(float)CD4,(float)CD5,(float)CD6,(float)CD7},
      {1.0f,(float)CD3,(float)CD6,(float)(-CD7),(float)(-CD4),(float)(-CD1),(float)(-CD2),(float)(-CD5)},
      {1.0f,(float)CD5,(float)(-CD6),(float)(-CD1),(float)(-CD4),(float)CD7,(float)CD2,(float)CD3},
      {1.0f,(float)CD7,(float)(-CD2),(float)(-CD5),(float)CD4,(float)CD3,(float)(-CD6),(float)(-CD1)},
      {1.0f,(float)(-CD7),(float)(-CD2),(float)CD5,(float)CD4,(float)(-CD3),(float)(-CD6),(float)CD1},
      {1.0f,(float)(-CD5),(float)(-CD6),(float)CD1,(float)(-CD4),(float)(-CD7),(float)CD2,(float)(-CD3)},
      {1.0f,(float)(-CD3),(float)CD6,(float)CD7,(float)(-CD4),(float)CD1,(float)(-CD2),(float)CD5},
      {1.0f,(float)(-CD1),(float)CD2,(float)(-CD3),(float)CD4,(float)(-CD5),(float)CD6,(float)(-CD7)}
    };

    const int tid = threadIdx.x;
    const int wg  = blockIdx.x;
    const int bc  = wg >> 9;            // 512 workgroups per (b,c) image
    const int rem = wg & 511;
    const int bh  = rem >> 2;           // block-row 0..127
    const int bwq = (rem & 3) * 32;     // first block (in W) of this wg's 32
    const int ch  = bc % 3;
    const int bb  = bc / 3;

    const size_t ibase = (size_t)bc * 1048576 + (size_t)bh * 8192 + (size_t)bwq * 8;

    // quant/dequant tables (runtime-v indexed -> must live in LDS, not per-thread arrays)
    if (tid < 64) {
        const int u = tid >> 3, v = tid & 7;
        const double a_u = u ? 1.0 : 0.7071067811865476;
        const double a_v = v ? 1.0 : 0.7071067811865476;
        const double qt  = (double)YLg[v * 8 + u] * 0.4;   // y_tab[u][v]
        const double al  = a_u * a_v;
        lds[2176 + tid] = (float)(al * 0.25 / qt);          // KQ = SCALE/y_tab
        lds[2240 + tid] = (float)(qt * al * 0.25);          // KD = y_tab*alpha*0.25
    }

    // ---- stage 0: global -> LDS (8 image rows x 1KB, fully coalesced) ----
#pragma unroll
    for (int j = 0; j < 2; ++j) {
        const int flat = j * 1024 + tid * 4;
        const int r = flat >> 8, c = flat & 255;
        const float4 val = *reinterpret_cast<const float4*>(in + ibase + (size_t)r * 1024 + c);
        *reinterpret_cast<float4*>(&lds[r * 260 + c]) = val;
    }
    __syncthreads();

    const int blk = tid >> 3;   // block 0..31 within wg
    const int p   = tid & 7;    // spatial row x (stages A/D) / freq col v (stages B/C)

    // ---- stage A: row DCT.  D1[v] = sum_y (m[y]*255-128) * CT[y][v] ----
    float d1[8];
    {
        const float4 m0 = *reinterpret_cast<const float4*>(&lds[p * 260 + blk * 8]);
        const float4 m1 = *reinterpret_cast<const float4*>(&lds[p * 260 + blk * 8 + 4]);
        float s[8] = {m0.x, m0.y, m0.z, m0.w, m1.x, m1.y, m1.z, m1.w};
#pragma unroll
        for (int y = 0; y < 8; ++y) s[y] = fmaf(s[y], 255.0f, -128.0f);
#pragma unroll
        for (int v = 0; v < 8; ++v) {
            float acc = 0.0f;
#pragma unroll
            for (int y = 0; y < 8; ++y) acc = fmaf(s[y], CT[y][v], acc);
            d1[v] = acc;
        }
    }
    __syncthreads();  // image-region reads done before record-region writes (they overlap)
    *reinterpret_cast<float4*>(&lds[blk * 68 + p * 8])     = make_float4(d1[0], d1[1], d1[2], d1[3]);
    *reinterpret_cast<float4*>(&lds[blk * 68 + p * 8 + 4]) = make_float4(d1[4], d1[5], d1[6], d1[7]);
    __syncthreads();

    // ---- stage B: column DCT + quant. thread owns column v=p of block blk ----
    // (column p is read and rewritten ONLY by this thread -> no barrier inside)
    float q[8], dq[8];
    {
        float c0[8];
#pragma unroll
        for (int x = 0; x < 8; ++x) c0[x] = lds[blk * 68 + x * 8 + p];
#pragma unroll
        for (int u = 0; u < 8; ++u) {
            float acc = 0.0f;
#pragma unroll
            for (int x = 0; x < 8; ++x) acc = fmaf(CT[x][u], c0[x], acc);
            const float kq = lds[2176 + u * 8 + p];
            const float kd = lds[2240 + u * 8 + p];
            const float xq = acc * kq;
            const float r  = rintf(xq);        // round half-to-even = jnp.round
            const float d  = xq - r;
            q[u]  = r + d * d * d;             // diff_round
            dq[u] = q[u] * kd;                 // dequant*alpha*0.25 for IDCT
        }
#pragma unroll
        for (int u = 0; u < 8; ++u) lds[blk * 68 + u * 8 + p] = q[u];
    }
    __syncthreads();

    // ---- q dump: wg's 32 records = 8KB contiguous, 1KB per wave-instruction ----
    {
        float* qb = out + (size_t)ch * 8388608 + (size_t)bb * 1048576
                        + ((size_t)(bh * 128) + bwq) * 64;
#pragma unroll
        for (int j = 0; j < 2; ++j) {
            const int flat = j * 1024 + tid * 4;
            const int rec = flat >> 6, off = flat & 63;
            const float4 val = *reinterpret_cast<const float4*>(&lds[rec * 68 + off]);
            *reinterpret_cast<float4*>(qb + flat) = val;
        }
    }

    // ---- stage C: column IDCT in registers: E1[x] = sum_u CT[x][u]*dq[u] ----
    float e1[8];
#pragma unroll
    for (int x = 0; x < 8; ++x) {
        float acc = 0.0f;
#pragma unroll
        for (int u = 0; u < 8; ++u) acc = fmaf(CT[x][u], dq[u], acc);
        e1[x] = acc;
    }
    __syncthreads();  // all q-dump reads complete before overwriting record region
#pragma unroll
    for (int x = 0; x < 8; ++x) lds[blk * 68 + x * 8 + p] = e1[x];
    __syncthreads();

    // ---- stage D: row IDCT + clip. thread owns spatial row x=p of block blk ----
    float orow[8];
    {
        const float4 a0 = *reinterpret_cast<const float4*>(&lds[blk * 68 + p * 8]);
        const float4 a1 = *reinterpret_cast<const float4*>(&lds[blk * 68 + p * 8 + 4]);
        const float e[8] = {a0.x, a0.y, a0.z, a0.w, a1.x, a1.y, a1.z, a1.w};
#pragma unroll
        for (int y = 0; y < 8; ++y) {
            float acc = 0.0f;
#pragma unroll
            for (int v = 0; v < 8; ++v) acc = fmaf(e[v], CT[y][v], acc);
            acc += 128.0f;
            acc = fminf(fmaxf(acc, 0.0f), 255.0f);
            orow[y] = acc * (1.0f / 255.0f);
        }
    }
    __syncthreads();  // record-region reads done before image-region writes (overlap)
    *reinterpret_cast<float4*>(&lds[p * 260 + blk * 8])     = make_float4(orow[0], orow[1], orow[2], orow[3]);
    *reinterpret_cast<float4*>(&lds[p * 260 + blk * 8 + 4]) = make_float4(orow[4], orow[5], orow[6], orow[7]);
    __syncthreads();

    // ---- rec dump: 8 image rows x 1KB, fully coalesced ----
    {
        float* rb = out + (size_t)25165824 + (size_t)bc * 1048576
                        + (size_t)bh * 8192 + (size_t)bwq * 8;
#pragma unroll
        for (int j = 0; j < 2; ++j) {
            const int flat = j * 1024 + tid * 4;
            const int r = flat >> 8, c = flat & 255;
            const float4 val = *reinterpret_cast<const float4*>(&lds[r * 260 + c]);
            *reinterpret_cast<float4*>(rb + (size_t)r * 1024 + c) = val;
        }
    }
}

extern "C" void kernel_launch(void* const* d_in, const int* in_sizes, int n_in,
                              void* d_out, int out_size, void* d_ws, size_t ws_size,
                              hipStream_t stream) {
    const float* x = (const float*)d_in[0];
    float*       o = (float*)d_out;
    // 393216 8x8-blocks, 8 threads/block, 256-thread workgroups -> 12288 wgs
    diffjpeg_kernel<<<12288, 256, 0, stream>>>(x, o);
}